// Round 13
// baseline (62.971 us; speedup 1.0000x reference)
//
#include <hip/hip_runtime.h>
#include <hip/hip_fp16.h>

#define NN 30000
#define DD 128
#define KK 32
#define OUTW 159   // 31 + 128
#define K2BLKS 1875   // 16 nodes per block
#define K3BLKS 1024

typedef __attribute__((ext_vector_type(8))) short bf16x8;
typedef __attribute__((ext_vector_type(4))) float f32x4;

static __device__ inline short f2bf(float f) {
  union { float f; unsigned u; } x; x.f = f;
  unsigned r = x.u + 0x7fffu + ((x.u >> 16) & 1u);   // RNE
  return (short)(r >> 16);
}

// ---------------- K1: z = h @ Wfc^T via MFMA bf16; fused dots; z -> fp16 --
__global__ __launch_bounds__(256) void k1_gemm(
    const float* __restrict__ h, const float* __restrict__ W,
    const float* __restrict__ Wa, const float* __restrict__ wr,
    __half* __restrict__ z, float* __restrict__ s, float* __restrict__ dv,
    float* __restrict__ zr0, float* __restrict__ zr1) {
  __shared__ char smem[48 * 1024];
  short* As = (short*)smem;               // 64*128 bf16, row stride 256B
  short* Bs = (short*)(smem + 16 * 1024); // 128*128 bf16, row stride 256B
  const int tid = threadIdx.x;
  const int row0 = blockIdx.x * 64;

#pragma unroll
  for (int q = 0; q < 4; q++) {
    int idx = q * 256 + tid;
    int r = idx >> 4, kq = idx & 15;
    int row = row0 + r;
    float v[8];
    if (row < NN) {
      float4 v0 = *(const float4*)(h + (long)row * DD + kq * 8);
      float4 v1 = *(const float4*)(h + (long)row * DD + kq * 8 + 4);
      v[0]=v0.x; v[1]=v0.y; v[2]=v0.z; v[3]=v0.w;
      v[4]=v1.x; v[5]=v1.y; v[6]=v1.z; v[7]=v1.w;
    } else {
#pragma unroll
      for (int j = 0; j < 8; j++) v[j] = 0.f;
    }
    bf16x8 b;
#pragma unroll
    for (int j = 0; j < 8; j++) b[j] = f2bf(v[j]);
    *(bf16x8*)((char*)As + r * 256 + ((kq * 16) ^ ((r & 7) << 4))) = b;
  }
#pragma unroll
  for (int q = 0; q < 8; q++) {
    int idx = q * 256 + tid;
    int j0 = idx >> 4, kq = idx & 15;
    float4 v0 = *(const float4*)(W + (long)j0 * DD + kq * 8);
    float4 v1 = *(const float4*)(W + (long)j0 * DD + kq * 8 + 4);
    float v[8] = {v0.x, v0.y, v0.z, v0.w, v1.x, v1.y, v1.z, v1.w};
    bf16x8 b;
#pragma unroll
    for (int jj = 0; jj < 8; jj++) b[jj] = f2bf(v[jj]);
    *(bf16x8*)((char*)Bs + j0 * 256 + ((kq * 16) ^ ((j0 & 7) << 4))) = b;
  }
  __syncthreads();

  const int wid = tid >> 6, lane = tid & 63;
  const int la = lane & 15, lb = lane >> 4;

  bf16x8 afr[4];
#pragma unroll
  for (int kc = 0; kc < 4; kc++) {
    int r = wid * 16 + la;
    int cb2 = (kc * 32 + lb * 8) * 2;
    afr[kc] = *(bf16x8*)((char*)As + r * 256 + (cb2 ^ ((la & 7) << 4)));
  }

  f32x4 acc[8];
#pragma unroll
  for (int cb = 0; cb < 8; cb++) acc[cb] = (f32x4){0.f, 0.f, 0.f, 0.f};

#pragma unroll
  for (int cb = 0; cb < 8; cb++) {
    int j = cb * 16 + la;
#pragma unroll
    for (int kc = 0; kc < 4; kc++) {
      int cb2 = (kc * 32 + lb * 8) * 2;
      bf16x8 bfr = *(bf16x8*)((char*)Bs + j * 256 + (cb2 ^ ((la & 7) << 4)));
      acc[cb] = __builtin_amdgcn_mfma_f32_16x16x32_bf16(afr[kc], bfr, acc[cb], 0, 0, 0);
    }
  }

  float sa[4] = {0,0,0,0}, da[4] = {0,0,0,0}, r0s[4] = {0,0,0,0}, r1s[4] = {0,0,0,0};
#pragma unroll
  for (int cb = 0; cb < 8; cb++) {
    int c = cb * 16 + la;
    float wa0 = Wa[c], wa1 = Wa[DD + c], w0 = wr[c], w1 = wr[DD + c];
#pragma unroll
    for (int rg = 0; rg < 4; rg++) {
      float zv = acc[cb][rg];
      sa[rg]  += zv * wa0; da[rg]  += zv * wa1;
      r0s[rg] += zv * w0;  r1s[rg] += zv * w1;
    }
  }
#pragma unroll
  for (int rg = 0; rg < 4; rg++) {
#pragma unroll
    for (int o = 1; o < 16; o <<= 1) {
      sa[rg]  += __shfl_xor(sa[rg], o);
      da[rg]  += __shfl_xor(da[rg], o);
      r0s[rg] += __shfl_xor(r0s[rg], o);
      r1s[rg] += __shfl_xor(r1s[rg], o);
    }
    int row = row0 + wid * 16 + lb * 4 + rg;
    if (la == 0 && row < NN) {
      s[row] = sa[rg]; dv[row] = da[rg]; zr0[row] = r0s[rg]; zr1[row] = r1s[rg];
    }
  }

  __syncthreads();
  __half* zl = (__half*)smem;             // 64 x 132 halfs
#pragma unroll
  for (int cb = 0; cb < 8; cb++) {
#pragma unroll
    for (int rg = 0; rg < 4; rg++) {
      int r = wid * 16 + lb * 4 + rg, c = cb * 16 + la;
      zl[r * 132 + c] = __float2half(acc[cb][rg]);
    }
  }
  __syncthreads();
  {
    int r = tid >> 2, c0 = (tid & 3) * 32;
    int row = row0 + r;
    if (row < NN) {
      const __half* src = zl + r * 132 + c0;
      int4 a0 = *(const int4*)(src);
      int4 a1 = *(const int4*)(src + 8);
      int4 a2 = *(const int4*)(src + 16);
      int4 a3 = *(const int4*)(src + 24);
      __half* dst = z + (long)row * DD + c0;
      *(int4*)(dst)      = a0;
      *(int4*)(dst + 8)  = a1;
      *(int4*)(dst + 16) = a2;
      *(int4*)(dst + 24) = a3;
    }
  }
}

// ---- K2: phase-split softmax, then batched-load gather bursts ------------
__global__ __launch_bounds__(256) void k2_main(
    const __half* __restrict__ z, const float* __restrict__ s,
    const float* __restrict__ dv, const float* __restrict__ zr0,
    const float* __restrict__ zr1, const int* __restrict__ nbr,
    const float* __restrict__ wc, const float* __restrict__ brp,
    const float* __restrict__ bcp,
    float* __restrict__ out, float* __restrict__ partials) {
  __shared__ float red[4][4];
  const int w = threadIdx.x >> 6, lane = threadIdx.x & 63;
  const int p = lane >> 4, m = lane & 15;
  const float br0 = brp[0], bc0 = bcp[0];
  float pr = 0.f, pr2 = 0.f, pc = 0.f, pc2 = 0.f;

  float aw_r[4];
  int base_r[4];

  // ---- phase 1: softmax + row outputs for 4 nodes ----
#pragma unroll
  for (int it = 0; it < 4; it++) {
    int i = blockIdx.x * 16 + w * 4 + it;     // < 30000 always
    float dvi = dv[i];
    float aw = 0.f; int base = 0;
    if (lane < KK) {
      int nk = nbr[i * KK + lane];
      float e = s[nk] + dvi;
      e = e > 0.f ? e : 0.01f * e;              // leaky_relu
      float mx = e;
#pragma unroll
      for (int o = 16; o; o >>= 1) mx = fmaxf(mx, __shfl_xor(mx, o, 32));
      float ex = __expf(e - mx);
      float sm = ex;
#pragma unroll
      for (int o = 16; o; o >>= 1) sm += __shfl_xor(sm, o, 32);
      float alpha = ex / sm;

      float t1 = alpha * zr1[nk];
      float t1n = __shfl_down(t1, 1, 32);
      if (lane < KK - 1) {
        float v = alpha * zr0[nk] + t1n + br0;
        __builtin_nontemporal_store(v, &out[(long)i * OUTW + lane]);
        pr += v; pr2 += v * v;
      }
      aw = alpha * wc[lane];
      base = nk * DD;                          // in half units
    }
    aw_r[it] = aw;
    base_r[it] = base;
  }

  // ---- phase 2: gather bursts, 8 loads batched before any use ----
#pragma unroll
  for (int it = 0; it < 4; it++) {
    int i = blockIdx.x * 16 + w * 4 + it;
    int offs[8];
#pragma unroll
    for (int t = 0; t < 8; t++) {
      int k = 4 * t + p;
      offs[t] = __shfl(base_r[it], k);
    }
    int4 raw[8];
#pragma unroll
    for (int t = 0; t < 8; t++)
      raw[t] = *(const int4*)(z + offs[t] + m * 8);

    float ac[8];
#pragma unroll
    for (int e = 0; e < 8; e++) ac[e] = 0.f;
#pragma unroll
    for (int t = 0; t < 8; t++) {
      int k = 4 * t + p;
      float a = __shfl(aw_r[it], k);
      const __half2* hp = (const __half2*)&raw[t];
      float2 f0 = __half22float2(hp[0]);
      float2 f1 = __half22float2(hp[1]);
      float2 f2 = __half22float2(hp[2]);
      float2 f3 = __half22float2(hp[3]);
      ac[0] += a * f0.x; ac[1] += a * f0.y;
      ac[2] += a * f1.x; ac[3] += a * f1.y;
      ac[4] += a * f2.x; ac[5] += a * f2.y;
      ac[6] += a * f3.x; ac[7] += a * f3.y;
    }
#pragma unroll
    for (int e = 0; e < 8; e++) {
      ac[e] += __shfl_xor(ac[e], 16);
      ac[e] += __shfl_xor(ac[e], 32);
      ac[e] += bc0;
    }
    if (p == 0) {                               // lanes 0..15, m = lane
      long ob = (long)i * OUTW + 31 + m * 8;
#pragma unroll
      for (int e = 0; e < 8; e++) {
        __builtin_nontemporal_store(ac[e], &out[ob + e]);
        pc += ac[e]; pc2 += ac[e] * ac[e];
      }
    }
  }

#pragma unroll
  for (int o = 32; o; o >>= 1) {
    pr  += __shfl_xor(pr, o);  pr2 += __shfl_xor(pr2, o);
    pc  += __shfl_xor(pc, o);  pc2 += __shfl_xor(pc2, o);
  }
  if (lane == 0) { red[w][0] = pr; red[w][1] = pr2; red[w][2] = pc; red[w][3] = pc2; }
  __syncthreads();
  if (threadIdx.x < 4) {
    float v = red[0][threadIdx.x] + red[1][threadIdx.x] +
              red[2][threadIdx.x] + red[3][threadIdx.x];
    partials[(long)blockIdx.x * 4 + threadIdx.x] = v;
  }
}

// ---- K3: per-block redundant partial reduce -> BN coef; apply BN+ReLU ----
__global__ __launch_bounds__(256) void k3_fused(
    float* __restrict__ out, const float* __restrict__ partials,
    const float* __restrict__ gr, const float* __restrict__ betar,
    const float* __restrict__ gc, const float* __restrict__ betac) {
  __shared__ float red[4][4];
  __shared__ float coefs[4];
  const int w = threadIdx.x >> 6, lane = threadIdx.x & 63;

  float v0 = 0.f, v1 = 0.f, v2 = 0.f, v3 = 0.f;
  for (int idx = threadIdx.x; idx < K2BLKS; idx += 256) {
    float4 p = ((const float4*)partials)[idx];
    v0 += p.x; v1 += p.y; v2 += p.z; v3 += p.w;
  }
#pragma unroll
  for (int o = 32; o; o >>= 1) {
    v0 += __shfl_xor(v0, o); v1 += __shfl_xor(v1, o);
    v2 += __shfl_xor(v2, o); v3 += __shfl_xor(v3, o);
  }
  if (lane == 0) { red[w][0] = v0; red[w][1] = v1; red[w][2] = v2; red[w][3] = v3; }
  __syncthreads();
  if (threadIdx.x == 0) {
    float sr  = red[0][0] + red[1][0] + red[2][0] + red[3][0];
    float sr2 = red[0][1] + red[1][1] + red[2][1] + red[3][1];
    float sc  = red[0][2] + red[1][2] + red[2][2] + red[3][2];
    float sc2 = red[0][3] + red[1][3] + red[2][3] + red[3][3];
    const float cntR = (float)NN * 31.0f, cntC = (float)NN * 128.0f;
    float mR = sr / cntR,  vR = sr2 / cntR - mR * mR;
    float mC = sc / cntC,  vC = sc2 / cntC - mC * mC;
    float scR = gr[0] * rsqrtf(vR + 1e-5f);
    float scC = gc[0] * rsqrtf(vC + 1e-5f);
    coefs[0] = scR; coefs[1] = betar[0] - mR * scR;
    coefs[2] = scC; coefs[3] = betac[0] - mC * scC;
  }
  __syncthreads();
  const float scR = coefs[0], shR = coefs[1], scC = coefs[2], shC = coefs[3];

  const int TOT4 = NN * OUTW / 4;   // 1,192,500 exactly
  float4* o4 = (float4*)out;
  for (int f = blockIdx.x * 256 + threadIdx.x; f < TOT4; f += K3BLKS * 256) {
    float4 x = o4[f];
    int j = (4 * f) % OUTW;
    float r[4] = {x.x, x.y, x.z, x.w};
#pragma unroll
    for (int e = 0; e < 4; e++) {
      bool isRow = j < 31;
      r[e] = fmaxf((isRow ? scR : scC) * r[e] + (isRow ? shR : shC), 0.f);
      j = (j == OUTW - 1) ? 0 : j + 1;
    }
    o4[f] = make_float4(r[0], r[1], r[2], r[3]);
  }
}

extern "C" void kernel_launch(void* const* d_in, const int* in_sizes, int n_in,
                              void* d_out, int out_size, void* d_ws, size_t ws_size,
                              hipStream_t stream) {
  const float* h     = (const float*)d_in[0];
  const float* Wfc   = (const float*)d_in[1];
  const float* Wa    = (const float*)d_in[2];
  const float* wr    = (const float*)d_in[3];
  const float* br    = (const float*)d_in[4];
  const float* gr    = (const float*)d_in[5];
  const float* betar = (const float*)d_in[6];
  const float* wc    = (const float*)d_in[7];
  const float* bc    = (const float*)d_in[8];
  const float* gc    = (const float*)d_in[9];
  const float* betac = (const float*)d_in[10];
  const int*   nbr   = (const int*)d_in[11];
  float* out = (float*)d_out;

  float* ws   = (float*)d_ws;
  __half* z   = (__half*)ws;                 // NN*DD halfs = NN*64 floats
  float* s    = ws + (long)NN * 64;          // NN
  float* dv   = s  + NN;
  float* zr0  = dv + NN;
  float* zr1  = zr0 + NN;
  float* partials = zr1 + NN;                // K2BLKS float4

  k1_gemm<<<(NN + 63) / 64, 256, 0, stream>>>(h, Wfc, Wa, wr, z, s, dv, zr0, zr1);
  k2_main<<<K2BLKS, 256, 0, stream>>>(z, s, dv, zr0, zr1, nbr, wc, br, bc, out, partials);
  k3_fused<<<K3BLKS, 256, 0, stream>>>(out, partials, gr, betar, gc, betac);
}

// Round 15
// 56.993 us; speedup vs baseline: 1.1049x; 1.1049x over previous
//
#include <hip/hip_runtime.h>
#include <hip/hip_fp16.h>

#define NN 30000
#define DD 128
#define KK 32
#define OUTW 159   // 31 + 128
#define K2BLKS 1875   // 16 nodes per block
#define K3BLKS 1024

typedef __attribute__((ext_vector_type(8))) short bf16x8;
typedef __attribute__((ext_vector_type(4))) float f32x4;

static __device__ inline short f2bf(float f) {
  union { float f; unsigned u; } x; x.f = f;
  unsigned r = x.u + 0x7fffu + ((x.u >> 16) & 1u);   // RNE
  return (short)(r >> 16);
}

// ---- K1: z = h @ Wfc^T via MFMA bf16; fused dots; z -> int8 row-quant ----
__global__ __launch_bounds__(256) void k1_gemm(
    const float* __restrict__ h, const float* __restrict__ W,
    const float* __restrict__ Wa, const float* __restrict__ wr,
    unsigned char* __restrict__ zq, float* __restrict__ s,
    float* __restrict__ dv, float* __restrict__ zr0,
    float* __restrict__ zr1, float* __restrict__ zsc) {
  __shared__ char smem[48 * 1024];
  short* As = (short*)smem;               // 64*128 bf16, row stride 256B
  short* Bs = (short*)(smem + 16 * 1024); // 128*128 bf16, row stride 256B
  const int tid = threadIdx.x;
  const int row0 = blockIdx.x * 64;

#pragma unroll
  for (int q = 0; q < 4; q++) {
    int idx = q * 256 + tid;
    int r = idx >> 4, kq = idx & 15;
    int row = row0 + r;
    float v[8];
    if (row < NN) {
      float4 v0 = *(const float4*)(h + (long)row * DD + kq * 8);
      float4 v1 = *(const float4*)(h + (long)row * DD + kq * 8 + 4);
      v[0]=v0.x; v[1]=v0.y; v[2]=v0.z; v[3]=v0.w;
      v[4]=v1.x; v[5]=v1.y; v[6]=v1.z; v[7]=v1.w;
    } else {
#pragma unroll
      for (int j = 0; j < 8; j++) v[j] = 0.f;
    }
    bf16x8 b;
#pragma unroll
    for (int j = 0; j < 8; j++) b[j] = f2bf(v[j]);
    *(bf16x8*)((char*)As + r * 256 + ((kq * 16) ^ ((r & 7) << 4))) = b;
  }
#pragma unroll
  for (int q = 0; q < 8; q++) {
    int idx = q * 256 + tid;
    int j0 = idx >> 4, kq = idx & 15;
    float4 v0 = *(const float4*)(W + (long)j0 * DD + kq * 8);
    float4 v1 = *(const float4*)(W + (long)j0 * DD + kq * 8 + 4);
    float v[8] = {v0.x, v0.y, v0.z, v0.w, v1.x, v1.y, v1.z, v1.w};
    bf16x8 b;
#pragma unroll
    for (int jj = 0; jj < 8; jj++) b[jj] = f2bf(v[jj]);
    *(bf16x8*)((char*)Bs + j0 * 256 + ((kq * 16) ^ ((j0 & 7) << 4))) = b;
  }
  __syncthreads();

  const int wid = tid >> 6, lane = tid & 63;
  const int la = lane & 15, lb = lane >> 4;

  bf16x8 afr[4];
#pragma unroll
  for (int kc = 0; kc < 4; kc++) {
    int r = wid * 16 + la;
    int cb2 = (kc * 32 + lb * 8) * 2;
    afr[kc] = *(bf16x8*)((char*)As + r * 256 + (cb2 ^ ((la & 7) << 4)));
  }

  f32x4 acc[8];
#pragma unroll
  for (int cb = 0; cb < 8; cb++) acc[cb] = (f32x4){0.f, 0.f, 0.f, 0.f};

#pragma unroll
  for (int cb = 0; cb < 8; cb++) {
    int j = cb * 16 + la;
#pragma unroll
    for (int kc = 0; kc < 4; kc++) {
      int cb2 = (kc * 32 + lb * 8) * 2;
      bf16x8 bfr = *(bf16x8*)((char*)Bs + j * 256 + (cb2 ^ ((la & 7) << 4)));
      acc[cb] = __builtin_amdgcn_mfma_f32_16x16x32_bf16(afr[kc], bfr, acc[cb], 0, 0, 0);
    }
  }

  float sa[4] = {0,0,0,0}, da[4] = {0,0,0,0}, r0s[4] = {0,0,0,0}, r1s[4] = {0,0,0,0};
  float mxr[4] = {1e-20f, 1e-20f, 1e-20f, 1e-20f};
#pragma unroll
  for (int cb = 0; cb < 8; cb++) {
    int c = cb * 16 + la;
    float wa0 = Wa[c], wa1 = Wa[DD + c], w0 = wr[c], w1 = wr[DD + c];
#pragma unroll
    for (int rg = 0; rg < 4; rg++) {
      float zv = acc[cb][rg];
      sa[rg]  += zv * wa0; da[rg]  += zv * wa1;
      r0s[rg] += zv * w0;  r1s[rg] += zv * w1;
      mxr[rg] = fmaxf(mxr[rg], fabsf(zv));
    }
  }
  float inv[4];
#pragma unroll
  for (int rg = 0; rg < 4; rg++) {
#pragma unroll
    for (int o = 1; o < 16; o <<= 1) {
      sa[rg]  += __shfl_xor(sa[rg], o);
      da[rg]  += __shfl_xor(da[rg], o);
      r0s[rg] += __shfl_xor(r0s[rg], o);
      r1s[rg] += __shfl_xor(r1s[rg], o);
      mxr[rg] = fmaxf(mxr[rg], __shfl_xor(mxr[rg], o));
    }
    inv[rg] = 127.f / mxr[rg];
    int row = row0 + wid * 16 + lb * 4 + rg;
    if (la == 0 && row < NN) {
      s[row] = sa[rg]; dv[row] = da[rg]; zr0[row] = r0s[rg]; zr1[row] = r1s[rg];
      zsc[row] = mxr[rg] * (1.f / 127.f);
    }
  }

  __syncthreads();
  unsigned char* zl = (unsigned char*)smem;   // 64 x 144 bytes (16B-aligned rows)
#pragma unroll
  for (int cb = 0; cb < 8; cb++) {
#pragma unroll
    for (int rg = 0; rg < 4; rg++) {
      int r = wid * 16 + lb * 4 + rg, c = cb * 16 + la;
      int qv = (int)rintf(acc[cb][rg] * inv[rg]) + 128;
      zl[r * 144 + c] = (unsigned char)qv;
    }
  }
  __syncthreads();
  {
    int r = tid >> 2, c0 = (tid & 3) * 32;
    int row = row0 + r;
    if (row < NN) {
      const unsigned char* src = zl + r * 144 + c0;
      int4 a0 = *(const int4*)(src);
      int4 a1 = *(const int4*)(src + 16);
      unsigned char* dst = zq + (long)row * DD + c0;
      *(int4*)(dst)      = a0;
      *(int4*)(dst + 16) = a1;
    }
  }
}

// ---- K2: phase-split softmax, int8 L2-resident gather --------------------
__global__ __launch_bounds__(256) void k2_main(
    const unsigned char* __restrict__ zq, const float* __restrict__ s,
    const float* __restrict__ dv, const float* __restrict__ zr0,
    const float* __restrict__ zr1, const float* __restrict__ zsc,
    const int* __restrict__ nbr, const float* __restrict__ wc,
    const float* __restrict__ brp, const float* __restrict__ bcp,
    float* __restrict__ out, float* __restrict__ partials) {
  __shared__ float red[4][4];
  const int w = threadIdx.x >> 6, lane = threadIdx.x & 63;
  const int p = lane >> 4, m = lane & 15;
  const float br0 = brp[0], bc0 = bcp[0];
  float pr = 0.f, pr2 = 0.f, pc = 0.f, pc2 = 0.f;

  float aw_r[4], asum_r[4];
  int base_r[4];

  // ---- phase 1: softmax + row outputs + scaled coefficients ----
#pragma unroll
  for (int it = 0; it < 4; it++) {
    int i = blockIdx.x * 16 + w * 4 + it;     // < 30000 always
    float dvi = dv[i];
    float aw = 0.f, awsum = 0.f; int base = 0;
    if (lane < KK) {
      int nk = nbr[i * KK + lane];
      float e = s[nk] + dvi;
      e = e > 0.f ? e : 0.01f * e;              // leaky_relu
      float mx = e;
#pragma unroll
      for (int o = 16; o; o >>= 1) mx = fmaxf(mx, __shfl_xor(mx, o, 32));
      float ex = __expf(e - mx);
      float sm = ex;
#pragma unroll
      for (int o = 16; o; o >>= 1) sm += __shfl_xor(sm, o, 32);
      float alpha = ex / sm;

      float t1 = alpha * zr1[nk];
      float t1n = __shfl_down(t1, 1, 32);
      if (lane < KK - 1) {
        float v = alpha * zr0[nk] + t1n + br0;
        out[(long)i * OUTW + lane] = v;
        pr += v; pr2 += v * v;
      }
      aw = alpha * wc[lane] * zsc[nk];          // scale folded in
      base = nk * DD;                           // byte offset
      awsum = aw;
#pragma unroll
      for (int o = 16; o; o >>= 1) awsum += __shfl_xor(awsum, o, 32);
    }
    aw_r[it] = aw; base_r[it] = base; asum_r[it] = awsum;
  }

  // ---- phase 2: int8 gather bursts (z fully L2-resident: 3.84 MB) ----
#pragma unroll
  for (int it = 0; it < 4; it++) {
    int i = blockIdx.x * 16 + w * 4 + it;
    float bcorr = bc0 - 128.f * __shfl(asum_r[it], 0);
    float ac[8];
#pragma unroll
    for (int e = 0; e < 8; e++) ac[e] = 0.f;
#pragma unroll
    for (int t = 0; t < 8; t++) {
      int k = 4 * t + p;
      float a = __shfl(aw_r[it], k);
      int off = __shfl(base_r[it], k);
      int2 raw = *(const int2*)(zq + off + m * 8);
      int wx = raw.x, wy = raw.y;
      ac[0] += a * (float)( wx        & 0xff);
      ac[1] += a * (float)((wx >> 8)  & 0xff);
      ac[2] += a * (float)((wx >> 16) & 0xff);
      ac[3] += a * (float)((unsigned)wx >> 24);
      ac[4] += a * (float)( wy        & 0xff);
      ac[5] += a * (float)((wy >> 8)  & 0xff);
      ac[6] += a * (float)((wy >> 16) & 0xff);
      ac[7] += a * (float)((unsigned)wy >> 24);
    }
#pragma unroll
    for (int e = 0; e < 8; e++) {
      ac[e] += __shfl_xor(ac[e], 16);
      ac[e] += __shfl_xor(ac[e], 32);
      ac[e] += bcorr;
    }
    if (p == 0) {                               // lanes 0..15, m = lane
      long ob = (long)i * OUTW + 31 + m * 8;
#pragma unroll
      for (int e = 0; e < 8; e++) {
        out[ob + e] = ac[e];
        pc += ac[e]; pc2 += ac[e] * ac[e];
      }
    }
  }

#pragma unroll
  for (int o = 32; o; o >>= 1) {
    pr  += __shfl_xor(pr, o);  pr2 += __shfl_xor(pr2, o);
    pc  += __shfl_xor(pc, o);  pc2 += __shfl_xor(pc2, o);
  }
  if (lane == 0) { red[w][0] = pr; red[w][1] = pr2; red[w][2] = pc; red[w][3] = pc2; }
  __syncthreads();
  if (threadIdx.x < 4) {
    float v = red[0][threadIdx.x] + red[1][threadIdx.x] +
              red[2][threadIdx.x] + red[3][threadIdx.x];
    partials[(long)blockIdx.x * 4 + threadIdx.x] = v;
  }
}

// ---- K3: per-block redundant partial reduce -> BN coef; apply BN+ReLU ----
__global__ __launch_bounds__(256) void k3_fused(
    float* __restrict__ out, const float* __restrict__ partials,
    const float* __restrict__ gr, const float* __restrict__ betar,
    const float* __restrict__ gc, const float* __restrict__ betac) {
  __shared__ float red[4][4];
  __shared__ float coefs[4];
  const int w = threadIdx.x >> 6, lane = threadIdx.x & 63;

  float v0 = 0.f, v1 = 0.f, v2 = 0.f, v3 = 0.f;
  for (int idx = threadIdx.x; idx < K2BLKS; idx += 256) {
    float4 p = ((const float4*)partials)[idx];
    v0 += p.x; v1 += p.y; v2 += p.z; v3 += p.w;
  }
#pragma unroll
  for (int o = 32; o; o >>= 1) {
    v0 += __shfl_xor(v0, o); v1 += __shfl_xor(v1, o);
    v2 += __shfl_xor(v2, o); v3 += __shfl_xor(v3, o);
  }
  if (lane == 0) { red[w][0] = v0; red[w][1] = v1; red[w][2] = v2; red[w][3] = v3; }
  __syncthreads();
  if (threadIdx.x == 0) {
    float sr  = red[0][0] + red[1][0] + red[2][0] + red[3][0];
    float sr2 = red[0][1] + red[1][1] + red[2][1] + red[3][1];
    float sc  = red[0][2] + red[1][2] + red[2][2] + red[3][2];
    float sc2 = red[0][3] + red[1][3] + red[2][3] + red[3][3];
    const float cntR = (float)NN * 31.0f, cntC = (float)NN * 128.0f;
    float mR = sr / cntR,  vR = sr2 / cntR - mR * mR;
    float mC = sc / cntC,  vC = sc2 / cntC - mC * mC;
    float scR = gr[0] * rsqrtf(vR + 1e-5f);
    float scC = gc[0] * rsqrtf(vC + 1e-5f);
    coefs[0] = scR; coefs[1] = betar[0] - mR * scR;
    coefs[2] = scC; coefs[3] = betac[0] - mC * scC;
  }
  __syncthreads();
  const float scR = coefs[0], shR = coefs[1], scC = coefs[2], shC = coefs[3];

  const int TOT4 = NN * OUTW / 4;   // 1,192,500 exactly
  float4* o4 = (float4*)out;
  for (int f = blockIdx.x * 256 + threadIdx.x; f < TOT4; f += K3BLKS * 256) {
    float4 x = o4[f];
    int j = (4 * f) % OUTW;
    float r[4] = {x.x, x.y, x.z, x.w};
#pragma unroll
    for (int e = 0; e < 4; e++) {
      bool isRow = j < 31;
      r[e] = fmaxf((isRow ? scR : scC) * r[e] + (isRow ? shR : shC), 0.f);
      j = (j == OUTW - 1) ? 0 : j + 1;
    }
    o4[f] = make_float4(r[0], r[1], r[2], r[3]);
  }
}

extern "C" void kernel_launch(void* const* d_in, const int* in_sizes, int n_in,
                              void* d_out, int out_size, void* d_ws, size_t ws_size,
                              hipStream_t stream) {
  const float* h     = (const float*)d_in[0];
  const float* Wfc   = (const float*)d_in[1];
  const float* Wa    = (const float*)d_in[2];
  const float* wr    = (const float*)d_in[3];
  const float* br    = (const float*)d_in[4];
  const float* gr    = (const float*)d_in[5];
  const float* betar = (const float*)d_in[6];
  const float* wc    = (const float*)d_in[7];
  const float* bc    = (const float*)d_in[8];
  const float* gc    = (const float*)d_in[9];
  const float* betac = (const float*)d_in[10];
  const int*   nbr   = (const int*)d_in[11];
  float* out = (float*)d_out;

  float* ws   = (float*)d_ws;
  unsigned char* zq = (unsigned char*)ws;    // NN*DD bytes = NN*32 floats
  float* s    = ws + (long)NN * 32;          // NN
  float* dv   = s   + NN;
  float* zr0  = dv  + NN;
  float* zr1  = zr0 + NN;
  float* zsc  = zr1 + NN;
  float* partials = zsc + NN;                // K2BLKS float4

  k1_gemm<<<(NN + 63) / 64, 256, 0, stream>>>(h, Wfc, Wa, wr, zq, s, dv, zr0, zr1, zsc);
  k2_main<<<K2BLKS, 256, 0, stream>>>(zq, s, dv, zr0, zr1, zsc, nbr, wc, br, bc, out, partials);
  k3_fused<<<K3BLKS, 256, 0, stream>>>(out, partials, gr, betar, gc, betac);
}

// Round 16
// 53.872 us; speedup vs baseline: 1.1689x; 1.0579x over previous
//
#include <hip/hip_runtime.h>
#include <hip/hip_fp16.h>

#define NN 30000
#define DD 128
#define KK 32
#define OUTW 159   // 31 + 128
#define K2BLKS 1875   // 16 nodes per block
#define K3BLKS 1024

typedef __attribute__((ext_vector_type(8))) short bf16x8;
typedef __attribute__((ext_vector_type(4))) float f32x4;

static __device__ inline short f2bf(float f) {
  union { float f; unsigned u; } x; x.f = f;
  unsigned r = x.u + 0x7fffu + ((x.u >> 16) & 1u);   // RNE
  return (short)(r >> 16);
}

// ---- K1: z = h @ Wfc^T via MFMA bf16; fused dots; z -> int8 row-quant ----
// Epilogue packs (s, zr0, zr1, zsc) into one float4 per row; dv separate.
__global__ __launch_bounds__(256) void k1_gemm(
    const float* __restrict__ h, const float* __restrict__ W,
    const float* __restrict__ Wa, const float* __restrict__ wr,
    unsigned char* __restrict__ zq, float4* __restrict__ srz2,
    float* __restrict__ dv) {
  __shared__ char smem[48 * 1024];
  short* As = (short*)smem;               // 64*128 bf16, row stride 256B
  short* Bs = (short*)(smem + 16 * 1024); // 128*128 bf16, row stride 256B
  const int tid = threadIdx.x;
  const int row0 = blockIdx.x * 64;

#pragma unroll
  for (int q = 0; q < 4; q++) {
    int idx = q * 256 + tid;
    int r = idx >> 4, kq = idx & 15;
    int row = row0 + r;
    float v[8];
    if (row < NN) {
      float4 v0 = *(const float4*)(h + (long)row * DD + kq * 8);
      float4 v1 = *(const float4*)(h + (long)row * DD + kq * 8 + 4);
      v[0]=v0.x; v[1]=v0.y; v[2]=v0.z; v[3]=v0.w;
      v[4]=v1.x; v[5]=v1.y; v[6]=v1.z; v[7]=v1.w;
    } else {
#pragma unroll
      for (int j = 0; j < 8; j++) v[j] = 0.f;
    }
    bf16x8 b;
#pragma unroll
    for (int j = 0; j < 8; j++) b[j] = f2bf(v[j]);
    *(bf16x8*)((char*)As + r * 256 + ((kq * 16) ^ ((r & 7) << 4))) = b;
  }
#pragma unroll
  for (int q = 0; q < 8; q++) {
    int idx = q * 256 + tid;
    int j0 = idx >> 4, kq = idx & 15;
    float4 v0 = *(const float4*)(W + (long)j0 * DD + kq * 8);
    float4 v1 = *(const float4*)(W + (long)j0 * DD + kq * 8 + 4);
    float v[8] = {v0.x, v0.y, v0.z, v0.w, v1.x, v1.y, v1.z, v1.w};
    bf16x8 b;
#pragma unroll
    for (int jj = 0; jj < 8; jj++) b[jj] = f2bf(v[jj]);
    *(bf16x8*)((char*)Bs + j0 * 256 + ((kq * 16) ^ ((j0 & 7) << 4))) = b;
  }
  __syncthreads();

  const int wid = tid >> 6, lane = tid & 63;
  const int la = lane & 15, lb = lane >> 4;

  bf16x8 afr[4];
#pragma unroll
  for (int kc = 0; kc < 4; kc++) {
    int r = wid * 16 + la;
    int cb2 = (kc * 32 + lb * 8) * 2;
    afr[kc] = *(bf16x8*)((char*)As + r * 256 + (cb2 ^ ((la & 7) << 4)));
  }

  f32x4 acc[8];
#pragma unroll
  for (int cb = 0; cb < 8; cb++) acc[cb] = (f32x4){0.f, 0.f, 0.f, 0.f};

#pragma unroll
  for (int cb = 0; cb < 8; cb++) {
    int j = cb * 16 + la;
#pragma unroll
    for (int kc = 0; kc < 4; kc++) {
      int cb2 = (kc * 32 + lb * 8) * 2;
      bf16x8 bfr = *(bf16x8*)((char*)Bs + j * 256 + (cb2 ^ ((la & 7) << 4)));
      acc[cb] = __builtin_amdgcn_mfma_f32_16x16x32_bf16(afr[kc], bfr, acc[cb], 0, 0, 0);
    }
  }

  float sa[4] = {0,0,0,0}, da[4] = {0,0,0,0}, r0s[4] = {0,0,0,0}, r1s[4] = {0,0,0,0};
  float mxr[4] = {1e-20f, 1e-20f, 1e-20f, 1e-20f};
#pragma unroll
  for (int cb = 0; cb < 8; cb++) {
    int c = cb * 16 + la;
    float wa0 = Wa[c], wa1 = Wa[DD + c], w0 = wr[c], w1 = wr[DD + c];
#pragma unroll
    for (int rg = 0; rg < 4; rg++) {
      float zv = acc[cb][rg];
      sa[rg]  += zv * wa0; da[rg]  += zv * wa1;
      r0s[rg] += zv * w0;  r1s[rg] += zv * w1;
      mxr[rg] = fmaxf(mxr[rg], fabsf(zv));
    }
  }
  float inv[4];
#pragma unroll
  for (int rg = 0; rg < 4; rg++) {
#pragma unroll
    for (int o = 1; o < 16; o <<= 1) {
      sa[rg]  += __shfl_xor(sa[rg], o);
      da[rg]  += __shfl_xor(da[rg], o);
      r0s[rg] += __shfl_xor(r0s[rg], o);
      r1s[rg] += __shfl_xor(r1s[rg], o);
      mxr[rg] = fmaxf(mxr[rg], __shfl_xor(mxr[rg], o));
    }
    inv[rg] = 127.f / mxr[rg];
    int row = row0 + wid * 16 + lb * 4 + rg;
    if (la == 0 && row < NN) {
      srz2[row] = make_float4(sa[rg], r0s[rg], r1s[rg], mxr[rg] * (1.f / 127.f));
      dv[row] = da[rg];
    }
  }

  __syncthreads();
  unsigned char* zl = (unsigned char*)smem;   // 64 x 144 bytes (16B-aligned rows)
#pragma unroll
  for (int cb = 0; cb < 8; cb++) {
#pragma unroll
    for (int rg = 0; rg < 4; rg++) {
      int r = wid * 16 + lb * 4 + rg, c = cb * 16 + la;
      int qv = (int)rintf(acc[cb][rg] * inv[rg]) + 128;
      zl[r * 144 + c] = (unsigned char)qv;
    }
  }
  __syncthreads();
  {
    int r = tid >> 2, c0 = (tid & 3) * 32;
    int row = row0 + r;
    if (row < NN) {
      const unsigned char* src = zl + r * 144 + c0;
      int4 a0 = *(const int4*)(src);
      int4 a1 = *(const int4*)(src + 16);
      unsigned char* dst = zq + (long)row * DD + c0;
      *(int4*)(dst)      = a0;
      *(int4*)(dst + 16) = a1;
    }
  }
}

// ---- K2: phase-split softmax (one packed gather), int8 z gather ----------
__global__ __launch_bounds__(256) void k2_main(
    const unsigned char* __restrict__ zq, const float4* __restrict__ srz2,
    const float* __restrict__ dv, const int* __restrict__ nbr,
    const float* __restrict__ wc, const float* __restrict__ brp,
    const float* __restrict__ bcp,
    float* __restrict__ out, float* __restrict__ partials) {
  __shared__ float red[4][4];
  const int w = threadIdx.x >> 6, lane = threadIdx.x & 63;
  const int p = lane >> 4, m = lane & 15;
  const float br0 = brp[0], bc0 = bcp[0];
  float pr = 0.f, pr2 = 0.f, pc = 0.f, pc2 = 0.f;

  float aw_r[4], asum_r[4];
  int base_r[4];

  // ---- phase 1: softmax + row outputs + scaled coefficients ----
#pragma unroll
  for (int it = 0; it < 4; it++) {
    int i = blockIdx.x * 16 + w * 4 + it;     // < 30000 always
    float dvi = dv[i];
    float aw = 0.f, awsum = 0.f; int base = 0;
    if (lane < KK) {
      int nk = nbr[i * KK + lane];
      float4 q = srz2[nk];                      // s, zr0, zr1, zsc
      float e = q.x + dvi;
      e = e > 0.f ? e : 0.01f * e;              // leaky_relu
      float mx = e;
#pragma unroll
      for (int o = 16; o; o >>= 1) mx = fmaxf(mx, __shfl_xor(mx, o, 32));
      float ex = __expf(e - mx);
      float sm = ex;
#pragma unroll
      for (int o = 16; o; o >>= 1) sm += __shfl_xor(sm, o, 32);
      float alpha = ex / sm;

      float t1 = alpha * q.z;
      float t1n = __shfl_down(t1, 1, 32);
      if (lane < KK - 1) {
        float v = alpha * q.y + t1n + br0;
        out[(long)i * OUTW + lane] = v;
        pr += v; pr2 += v * v;
      }
      aw = alpha * wc[lane] * q.w;              // zsc folded in
      base = nk * DD;                           // byte offset
      awsum = aw;
#pragma unroll
      for (int o = 16; o; o >>= 1) awsum += __shfl_xor(awsum, o, 32);
    }
    aw_r[it] = aw; base_r[it] = base; asum_r[it] = awsum;
  }

  // ---- phase 2: int8 gather bursts (z fully L2-resident: 3.84 MB) ----
#pragma unroll
  for (int it = 0; it < 4; it++) {
    int i = blockIdx.x * 16 + w * 4 + it;
    float bcorr = bc0 - 128.f * __shfl(asum_r[it], 0);
    float ac[8];
#pragma unroll
    for (int e = 0; e < 8; e++) ac[e] = 0.f;
#pragma unroll
    for (int t = 0; t < 8; t++) {
      int k = 4 * t + p;
      float a = __shfl(aw_r[it], k);
      int off = __shfl(base_r[it], k);
      int2 raw = *(const int2*)(zq + off + m * 8);
      int wx = raw.x, wy = raw.y;
      ac[0] += a * (float)( wx        & 0xff);
      ac[1] += a * (float)((wx >> 8)  & 0xff);
      ac[2] += a * (float)((wx >> 16) & 0xff);
      ac[3] += a * (float)((unsigned)wx >> 24);
      ac[4] += a * (float)( wy        & 0xff);
      ac[5] += a * (float)((wy >> 8)  & 0xff);
      ac[6] += a * (float)((wy >> 16) & 0xff);
      ac[7] += a * (float)((unsigned)wy >> 24);
    }
#pragma unroll
    for (int e = 0; e < 8; e++) {
      ac[e] += __shfl_xor(ac[e], 16);
      ac[e] += __shfl_xor(ac[e], 32);
      ac[e] += bcorr;
    }
    if (p == 0) {                               // lanes 0..15, m = lane
      long ob = (long)i * OUTW + 31 + m * 8;
#pragma unroll
      for (int e = 0; e < 8; e++) {
        out[ob + e] = ac[e];
        pc += ac[e]; pc2 += ac[e] * ac[e];
      }
    }
  }

#pragma unroll
  for (int o = 32; o; o >>= 1) {
    pr  += __shfl_xor(pr, o);  pr2 += __shfl_xor(pr2, o);
    pc  += __shfl_xor(pc, o);  pc2 += __shfl_xor(pc2, o);
  }
  if (lane == 0) { red[w][0] = pr; red[w][1] = pr2; red[w][2] = pc; red[w][3] = pc2; }
  __syncthreads();
  if (threadIdx.x < 4) {
    float v = red[0][threadIdx.x] + red[1][threadIdx.x] +
              red[2][threadIdx.x] + red[3][threadIdx.x];
    partials[(long)blockIdx.x * 4 + threadIdx.x] = v;
  }
}

// ---- K3: per-block redundant partial reduce -> BN coef; apply BN+ReLU ----
__global__ __launch_bounds__(256) void k3_fused(
    float* __restrict__ out, const float* __restrict__ partials,
    const float* __restrict__ gr, const float* __restrict__ betar,
    const float* __restrict__ gc, const float* __restrict__ betac) {
  __shared__ float red[4][4];
  __shared__ float coefs[4];
  const int w = threadIdx.x >> 6, lane = threadIdx.x & 63;

  float v0 = 0.f, v1 = 0.f, v2 = 0.f, v3 = 0.f;
  for (int idx = threadIdx.x; idx < K2BLKS; idx += 256) {
    float4 p = ((const float4*)partials)[idx];
    v0 += p.x; v1 += p.y; v2 += p.z; v3 += p.w;
  }
#pragma unroll
  for (int o = 32; o; o >>= 1) {
    v0 += __shfl_xor(v0, o); v1 += __shfl_xor(v1, o);
    v2 += __shfl_xor(v2, o); v3 += __shfl_xor(v3, o);
  }
  if (lane == 0) { red[w][0] = v0; red[w][1] = v1; red[w][2] = v2; red[w][3] = v3; }
  __syncthreads();
  if (threadIdx.x == 0) {
    float sr  = red[0][0] + red[1][0] + red[2][0] + red[3][0];
    float sr2 = red[0][1] + red[1][1] + red[2][1] + red[3][1];
    float sc  = red[0][2] + red[1][2] + red[2][2] + red[3][2];
    float sc2 = red[0][3] + red[1][3] + red[2][3] + red[3][3];
    const float cntR = (float)NN * 31.0f, cntC = (float)NN * 128.0f;
    float mR = sr / cntR,  vR = sr2 / cntR - mR * mR;
    float mC = sc / cntC,  vC = sc2 / cntC - mC * mC;
    float scR = gr[0] * rsqrtf(vR + 1e-5f);
    float scC = gc[0] * rsqrtf(vC + 1e-5f);
    coefs[0] = scR; coefs[1] = betar[0] - mR * scR;
    coefs[2] = scC; coefs[3] = betac[0] - mC * scC;
  }
  __syncthreads();
  const float scR = coefs[0], shR = coefs[1], scC = coefs[2], shC = coefs[3];

  const int TOT4 = NN * OUTW / 4;   // 1,192,500 exactly
  float4* o4 = (float4*)out;
  for (int f = blockIdx.x * 256 + threadIdx.x; f < TOT4; f += K3BLKS * 256) {
    float4 x = o4[f];
    int j = (4 * f) % OUTW;
    float r[4] = {x.x, x.y, x.z, x.w};
#pragma unroll
    for (int e = 0; e < 4; e++) {
      bool isRow = j < 31;
      r[e] = fmaxf((isRow ? scR : scC) * r[e] + (isRow ? shR : shC), 0.f);
      j = (j == OUTW - 1) ? 0 : j + 1;
    }
    o4[f] = make_float4(r[0], r[1], r[2], r[3]);
  }
}

extern "C" void kernel_launch(void* const* d_in, const int* in_sizes, int n_in,
                              void* d_out, int out_size, void* d_ws, size_t ws_size,
                              hipStream_t stream) {
  const float* h     = (const float*)d_in[0];
  const float* Wfc   = (const float*)d_in[1];
  const float* Wa    = (const float*)d_in[2];
  const float* wr    = (const float*)d_in[3];
  const float* br    = (const float*)d_in[4];
  const float* gr    = (const float*)d_in[5];
  const float* betar = (const float*)d_in[6];
  const float* wc    = (const float*)d_in[7];
  const float* bc    = (const float*)d_in[8];
  const float* gc    = (const float*)d_in[9];
  const float* betac = (const float*)d_in[10];
  const int*   nbr   = (const int*)d_in[11];
  float* out = (float*)d_out;

  float* ws   = (float*)d_ws;
  unsigned char* zq = (unsigned char*)ws;      // NN*DD bytes = NN*32 floats
  float4* srz2 = (float4*)(ws + (long)NN * 32);// NN float4 (16B aligned)
  float* dv   = (float*)(srz2 + NN);           // NN
  float* partials = dv + NN;                   // K2BLKS float4

  k1_gemm<<<(NN + 63) / 64, 256, 0, stream>>>(h, Wfc, Wa, wr, zq, srz2, dv);
  k2_main<<<K2BLKS, 256, 0, stream>>>(zq, srz2, dv, nbr, wc, br, bc, out, partials);
  k3_fused<<<K3BLKS, 256, 0, stream>>>(out, partials, gr, betar, gc, betac);
}